// Round 1
// baseline (6571.324 us; speedup 1.0000x reference)
//
#include <hip/hip_runtime.h>
#include <cstdint>
#include <cstddef>

// GPT2-MLA forward, MI355X. Round 0: correctness-first, bf16-MFMA GEMMs.
// B=2, T=1024, D=768, L=12, H=12, HD=64, DL=256, V=50257 (pad 50304 = 393*128)

typedef unsigned short ushortT;
typedef __bf16 bf16x8 __attribute__((ext_vector_type(8)));
typedef float f32x4 __attribute__((ext_vector_type(4)));
typedef unsigned short us8 __attribute__((ext_vector_type(8)));

#define NHEAD 12
#define T_SEQ 1024

__device__ __forceinline__ float bf2f(unsigned short u) {
    union { unsigned int i; float f; } v; v.i = ((unsigned int)u) << 16; return v.f;
}
__device__ __forceinline__ unsigned short f2bf(float f) {
    union { float f; unsigned int i; } v; v.f = f;
    unsigned int r = v.i + 0x7fffu + ((v.i >> 16) & 1u);
    return (unsigned short)(r >> 16);
}
__device__ __forceinline__ float readlane_f(float v, int l) {
    return __uint_as_float(__builtin_amdgcn_readlane(__float_as_uint(v), l));
}
__device__ __forceinline__ void gload_lds16(const void* g, void* l) {
    __builtin_amdgcn_global_load_lds((__attribute__((address_space(1))) void*)g,
                                     (__attribute__((address_space(3))) void*)l, 16, 0, 0);
}

// ---------------- weight convert / transpose ----------------
// in: f32 [L][K][N] -> out: bf16 [L][N][K]   grid(N/32, K/32, L), block(32,8)
__global__ void transpose_cvt_kernel(const float* __restrict__ in, ushortT* __restrict__ outp,
                                     int K, int N) {
    __shared__ float tile[32][33];
    const int tx = threadIdx.x, ty = threadIdx.y;
    const size_t loff = (size_t)blockIdx.z * K * N;
    const int n0 = blockIdx.x * 32, k0 = blockIdx.y * 32;
    const float* src = in + loff;
#pragma unroll
    for (int j = 0; j < 4; ++j)
        tile[ty + j * 8][tx] = src[(size_t)(k0 + ty + j * 8) * N + n0 + tx];
    __syncthreads();
    ushortT* dst = outp + loff;
#pragma unroll
    for (int j = 0; j < 4; ++j)
        dst[(size_t)(n0 + ty + j * 8) * K + k0 + tx] = f2bf(tile[tx][ty + j * 8]);
}

// wte f32 [50257*768] -> bf16 [50304*768] zero-padded; processes float4 units
__global__ void cvt_wte_kernel(const float* __restrict__ in, ushortT* __restrict__ outp) {
    size_t i4 = (size_t)blockIdx.x * 256 + threadIdx.x;  // over 50304*768/4 = 9658368
    ushort4 o;
    if (i4 < 9649344) {  // 50257*768/4
        float4 v = ((const float4*)in)[i4];
        o.x = f2bf(v.x); o.y = f2bf(v.y); o.z = f2bf(v.z); o.w = f2bf(v.w);
    } else { o.x = 0; o.y = 0; o.z = 0; o.w = 0; }
    ((ushort4*)outp)[i4] = o;
}

// ---------------- embedding ----------------
__global__ void embed_kernel(const int* __restrict__ idx, const float* __restrict__ wte,
                             const float* __restrict__ wpe, float* __restrict__ x) {
    int i = blockIdx.x * 256 + threadIdx.x;  // 2048*768
    int row = i / 768, d = i - row * 768;
    int t = row & 1023;
    x[i] = wte[(size_t)idx[row] * 768 + d] + wpe[(size_t)t * 768 + d];
}

// ---------------- rope ----------------
__global__ void rope_tables_kernel(float* __restrict__ cosT, float* __restrict__ sinT) {
    int i = blockIdx.x * 256 + threadIdx.x;  // 1024*32
    int t = i >> 5, f = i & 31;
    float invf = exp2f(-(float)f * (13.287712379549449f / 32.0f));  // 10000^(-f/32)
    float ang = (float)t * invf;
    cosT[i] = cosf(ang);
    sinT[i] = sinf(ang);
}

// x: bf16 rows [2048][stride], head block h*64, rotate halves per RoPE
__global__ void rope_apply_kernel(ushortT* __restrict__ x, int stride,
                                  const float* __restrict__ cosT, const float* __restrict__ sinT) {
    int i = blockIdx.x * 256 + threadIdx.x;  // 2048*12*32
    int row = i / 384, r = i - row * 384;
    int h = r >> 5, f = r & 31;
    int t = row & 1023;
    size_t base = (size_t)row * stride + h * 64 + f;
    float x1 = bf2f(x[base]), x2 = bf2f(x[base + 32]);
    float c = cosT[t * 32 + f], s = sinT[t * 32 + f];
    x[base] = f2bf(x1 * c - x2 * s);
    x[base + 32] = f2bf(x2 * c + x1 * s);
}

// ---------------- layernorm: f32 in -> bf16 out, D=768, block=256, grid=rows ----------------
__global__ __launch_bounds__(256) void ln_kernel(const float* __restrict__ x,
                                                 const float* __restrict__ wg,
                                                 const float* __restrict__ bg,
                                                 ushortT* __restrict__ outp) {
    const int row = blockIdx.x, tid = threadIdx.x;
    const float* xr = x + (size_t)row * 768;
    float v0 = xr[tid], v1 = xr[tid + 256], v2 = xr[tid + 512];
    float s = v0 + v1 + v2;
    float ss = v0 * v0 + v1 * v1 + v2 * v2;
#pragma unroll
    for (int off = 32; off >= 1; off >>= 1) {
        s += __shfl_xor(s, off);
        ss += __shfl_xor(ss, off);
    }
    __shared__ float sb[4], ssb[4];
    if ((tid & 63) == 0) { sb[tid >> 6] = s; ssb[tid >> 6] = ss; }
    __syncthreads();
    float S = sb[0] + sb[1] + sb[2] + sb[3];
    float SS = ssb[0] + ssb[1] + ssb[2] + ssb[3];
    const float mean = S * (1.0f / 768.0f);
    float var = SS * (1.0f / 768.0f) - mean * mean;
    const float rs = rsqrtf(var + 1e-5f);
    ushortT* orow = outp + (size_t)row * 768;
    orow[tid]       = f2bf((v0 - mean) * rs * wg[tid]       + bg[tid]);
    orow[tid + 256] = f2bf((v1 - mean) * rs * wg[tid + 256] + bg[tid + 256]);
    orow[tid + 512] = f2bf((v2 - mean) * rs * wg[tid + 512] + bg[tid + 512]);
}

// ---------------- GEMM: C[2048 x Nstore] = A[2048 x K](bf16) @ Bt[N x K](bf16)^T ----------------
// m97-style: 128x128 tile, BK=32, 4 waves each 64x64 (4x4 frags of 16x16x32 MFMA),
// global_load_lds width-16 staging. grid = (Npad/128, 16), block = 256.
__global__ __launch_bounds__(256) void gemm_kernel(
    const ushortT* __restrict__ A, const ushortT* __restrict__ Bt,
    int K, int Nstore,
    const float* __restrict__ bias, const float* __restrict__ resid,
    int act, float* __restrict__ outF, ushortT* __restrict__ outB) {
    __shared__ __align__(16) ushortT As[128 * 32];
    __shared__ __align__(16) ushortT Bs[128 * 32];
    const int tid = threadIdx.x;
    const int w = tid >> 6, lane = tid & 63;
    const int m0 = blockIdx.y * 128, n0 = blockIdx.x * 128;
    const int fr = lane & 15, kg = lane >> 4;
    const int wm = w >> 1, wn = w & 1;
    f32x4 acc[4][4] = {};
    const char* Ab = (const char*)A;
    const char* Bb = (const char*)Bt;
    const size_t Kb = (size_t)K * 2;

    for (int kt = 0; kt < K; kt += 32) {
        __syncthreads();
        const size_t ktb = (size_t)kt * 2;
#pragma unroll
        for (int i = 0; i < 2; ++i) {
            const int seg = (w * 2 + i) * 1024;
            const int loff = seg + lane * 16;
            const int row = loff >> 6, colb = loff & 63;  // 64 B per LDS row (32 bf16)
            gload_lds16(Ab + (size_t)(m0 + row) * Kb + ktb + colb, (char*)As + seg);
            gload_lds16(Bb + (size_t)(n0 + row) * Kb + ktb + colb, (char*)Bs + seg);
        }
        __syncthreads();
        bf16x8 af[4], bfr[4];
#pragma unroll
        for (int mf = 0; mf < 4; ++mf)
            af[mf] = *(const bf16x8*)(As + ((wm * 64 + mf * 16 + fr) * 32 + kg * 8));
#pragma unroll
        for (int nf = 0; nf < 4; ++nf)
            bfr[nf] = *(const bf16x8*)(Bs + ((wn * 64 + nf * 16 + fr) * 32 + kg * 8));
#pragma unroll
        for (int mf = 0; mf < 4; ++mf)
#pragma unroll
            for (int nf = 0; nf < 4; ++nf)
                acc[mf][nf] = __builtin_amdgcn_mfma_f32_16x16x32_bf16(
                    af[mf], bfr[nf], acc[mf][nf], 0, 0, 0);
    }

    // epilogue: C row = (lane>>4)*4 + reg, col = lane&15  [m89 verified layout]
#pragma unroll
    for (int mf = 0; mf < 4; ++mf) {
#pragma unroll
        for (int nf = 0; nf < 4; ++nf) {
            const int gcol = n0 + wn * 64 + nf * 16 + fr;
            if (gcol >= Nstore) continue;
            const float bv = bias ? bias[gcol] : 0.0f;
#pragma unroll
            for (int j = 0; j < 4; ++j) {
                const int grow = m0 + wm * 64 + mf * 16 + kg * 4 + j;
                float v = acc[mf][nf][j] + bv;
                const size_t ci = (size_t)grow * (size_t)Nstore + gcol;
                if (resid) v += resid[ci];
                if (act) v = 0.5f * v * (1.0f + erff(v * 0.70710678118654752f));
                if (outF) outF[ci] = v;
                if (outB) outB[ci] = f2bf(v);
            }
        }
    }
}

// ---------------- attention ----------------
// Block: 256 thr = 4 waves; each wave owns 4 consecutive q rows of one (b,h).
// K/V staged per 64-row chunk into LDS as f32 [64][65] (conflict-free columns).
// Scores kept in regs p[4][16] (s = c*64 + lane), softmax in regs, then PV.
__global__ __launch_bounds__(256) void attn_kernel(const ushortT* __restrict__ q,
                                                   const ushortT* __restrict__ kv,
                                                   ushortT* __restrict__ attnb) {
    __shared__ float ks[64][65];
    const int tid = threadIdx.x, w = tid >> 6, lane = tid & 63;
    const int qb = blockIdx.x * 16;  // 16 rows per block
    const int b = blockIdx.y / NHEAD, h = blockIdx.y % NHEAD;
    const int t0 = qb + w * 4;
    const size_t qrow0 = (size_t)b * T_SEQ + t0;

    float qreg[4];
#pragma unroll
    for (int r = 0; r < 4; ++r)
        qreg[r] = bf2f(q[(qrow0 + r) * 768 + h * 64 + lane]);

    float p[4][16];
#pragma unroll
    for (int r = 0; r < 4; ++r)
#pragma unroll
        for (int c = 0; c < 16; ++c) p[r][c] = -1e30f;

    const int nc = (qb >> 6) + 1;  // chunks of 64 needed (qb+15 < qb+64)
    const ushortT* kbase = kv + (size_t)b * T_SEQ * 1536 + h * 64;
    const ushortT* vbase = kbase + 768;
    const int rr = tid >> 2, dg = tid & 3;

    // ---- phase 1: scores ----
#pragma unroll
    for (int c = 0; c < 16; ++c) {
        if (c >= nc) break;
        __syncthreads();
        {
            const ushortT* src = kbase + (size_t)(c * 64 + rr) * 1536 + dg * 16;
            us8 u0 = *(const us8*)src, u1 = *(const us8*)(src + 8);
#pragma unroll
            for (int j = 0; j < 8; ++j) {
                ks[rr][dg * 16 + j] = bf2f(u0[j]);
                ks[rr][dg * 16 + 8 + j] = bf2f(u1[j]);
            }
        }
        __syncthreads();
        const int s = c * 64 + lane;
        float a0 = 0.f, a1 = 0.f, a2 = 0.f, a3 = 0.f;
#pragma unroll
        for (int d = 0; d < 64; ++d) {
            const float kd = ks[lane][d];
            a0 += readlane_f(qreg[0], d) * kd;
            a1 += readlane_f(qreg[1], d) * kd;
            a2 += readlane_f(qreg[2], d) * kd;
            a3 += readlane_f(qreg[3], d) * kd;
        }
        if (s <= t0)     p[0][c] = a0 * 0.125f;
        if (s <= t0 + 1) p[1][c] = a1 * 0.125f;
        if (s <= t0 + 2) p[2][c] = a2 * 0.125f;
        if (s <= t0 + 3) p[3][c] = a3 * 0.125f;
    }

    // ---- softmax (registers only) ----
    float li[4];
#pragma unroll
    for (int r = 0; r < 4; ++r) {
        float mm = -1e30f;
#pragma unroll
        for (int c = 0; c < 16; ++c) mm = fmaxf(mm, p[r][c]);
#pragma unroll
        for (int off = 32; off >= 1; off >>= 1) mm = fmaxf(mm, __shfl_xor(mm, off));
        float ll = 0.f;
#pragma unroll
        for (int c = 0; c < 16; ++c) {
            float e = __expf(p[r][c] - mm);  // masked (-1e30) -> 0
            p[r][c] = e;
            ll += e;
        }
#pragma unroll
        for (int off = 32; off >= 1; off >>= 1) ll += __shfl_xor(ll, off);
        li[r] = 1.0f / ll;
    }

    // ---- phase 2: PV ----
    float o[4] = {0.f, 0.f, 0.f, 0.f};
#pragma unroll
    for (int c = 0; c < 16; ++c) {
        if (c >= nc) break;
        __syncthreads();
        {
            const ushortT* src = vbase + (size_t)(c * 64 + rr) * 1536 + dg * 16;
            us8 u0 = *(const us8*)src, u1 = *(const us8*)(src + 8);
#pragma unroll
            for (int j = 0; j < 8; ++j) {
                ks[rr][dg * 16 + j] = bf2f(u0[j]);
                ks[rr][dg * 16 + 8 + j] = bf2f(u1[j]);
            }
        }
        __syncthreads();
#pragma unroll
        for (int sl = 0; sl < 64; ++sl) {
            const float vv = ks[sl][lane];
            o[0] += readlane_f(p[0][c], sl) * vv;
            o[1] += readlane_f(p[1][c], sl) * vv;
            o[2] += readlane_f(p[2][c], sl) * vv;
            o[3] += readlane_f(p[3][c], sl) * vv;
        }
    }
#pragma unroll
    for (int r = 0; r < 4; ++r)
        attnb[(qrow0 + r) * 768 + h * 64 + lane] = f2bf(o[r] * li[r]);
}

// ---------------- host ----------------
extern "C" void kernel_launch(void* const* d_in, const int* in_sizes, int n_in,
                              void* d_out, int out_size, void* d_ws, size_t ws_size,
                              hipStream_t stream) {
    (void)in_sizes; (void)n_in; (void)out_size; (void)ws_size;
    const int*   idxp   = (const int*)d_in[0];
    const float* wte    = (const float*)d_in[1];
    const float* wpe    = (const float*)d_in[2];
    const float* ln1_w  = (const float*)d_in[3];
    const float* ln1_b  = (const float*)d_in[4];
    const float* wq_w   = (const float*)d_in[5];
    const float* wq_b   = (const float*)d_in[6];
    const float* kva_w  = (const float*)d_in[7];
    const float* kva_b  = (const float*)d_in[8];
    const float* kvb_w  = (const float*)d_in[9];
    const float* kvb_b  = (const float*)d_in[10];
    const float* out_w  = (const float*)d_in[11];
    const float* out_b  = (const float*)d_in[12];
    const float* ln2_w  = (const float*)d_in[13];
    const float* ln2_b  = (const float*)d_in[14];
    const float* fc_w   = (const float*)d_in[15];
    const float* fc_b   = (const float*)d_in[16];
    const float* proj_w = (const float*)d_in[17];
    const float* proj_b = (const float*)d_in[18];
    const float* lnf_w  = (const float*)d_in[19];
    const float* lnf_b  = (const float*)d_in[20];

    char* ws = (char*)d_ws;
    size_t off = 0;
    auto alloc = [&](size_t bytes) -> char* {
        char* p = ws + off;
        off += (bytes + 255) & ~(size_t)255;
        return p;
    };
    // bf16 transposed weights [N][K] per layer
    ushortT* wqT   = (ushortT*)alloc((size_t)12 * 768 * 768 * 2);
    ushortT* kvaT  = (ushortT*)alloc((size_t)12 * 768 * 256 * 2);
    ushortT* kvbT  = (ushortT*)alloc((size_t)12 * 256 * 1536 * 2);
    ushortT* outT  = (ushortT*)alloc((size_t)12 * 768 * 768 * 2);
    ushortT* fcT   = (ushortT*)alloc((size_t)12 * 768 * 3072 * 2);
    ushortT* projT = (ushortT*)alloc((size_t)12 * 3072 * 768 * 2);
    ushortT* wteB  = (ushortT*)alloc((size_t)50304 * 768 * 2);  // padded, zero rows >= V
    float* cosT = (float*)alloc((size_t)1024 * 32 * 4);
    float* sinT = (float*)alloc((size_t)1024 * 32 * 4);
    float*   x     = (float*)alloc((size_t)2048 * 768 * 4);
    ushortT* h     = (ushortT*)alloc((size_t)2048 * 768 * 2);
    ushortT* qbuf  = (ushortT*)alloc((size_t)2048 * 768 * 2);
    ushortT* lat   = (ushortT*)alloc((size_t)2048 * 256 * 2);
    ushortT* kvbuf = (ushortT*)alloc((size_t)2048 * 1536 * 2);
    ushortT* attnb = (ushortT*)alloc((size_t)2048 * 768 * 2);
    ushortT* fca   = (ushortT*)alloc((size_t)2048 * 3072 * 2);

    const dim3 blkT(32, 8);
    // weight conversion (every call; deterministic)
    transpose_cvt_kernel<<<dim3(24, 24, 12), blkT, 0, stream>>>(wq_w,   wqT,   768, 768);
    transpose_cvt_kernel<<<dim3(8,  24, 12), blkT, 0, stream>>>(kva_w,  kvaT,  768, 256);
    transpose_cvt_kernel<<<dim3(48, 8,  12), blkT, 0, stream>>>(kvb_w,  kvbT,  256, 1536);
    transpose_cvt_kernel<<<dim3(24, 24, 12), blkT, 0, stream>>>(out_w,  outT,  768, 768);
    transpose_cvt_kernel<<<dim3(96, 24, 12), blkT, 0, stream>>>(fc_w,   fcT,   768, 3072);
    transpose_cvt_kernel<<<dim3(24, 96, 12), blkT, 0, stream>>>(proj_w, projT, 3072, 768);
    cvt_wte_kernel<<<37728, 256, 0, stream>>>(wte, wteB);
    rope_tables_kernel<<<128, 256, 0, stream>>>(cosT, sinT);
    embed_kernel<<<6144, 256, 0, stream>>>(idxp, wte, wpe, x);

    for (int l = 0; l < 12; ++l) {
        ln_kernel<<<2048, 256, 0, stream>>>(x, ln1_w + l * 768, ln1_b + l * 768, h);
        gemm_kernel<<<dim3(6, 16), 256, 0, stream>>>(h, wqT + (size_t)l * 768 * 768, 768, 768,
            wq_b + l * 768, nullptr, 0, nullptr, qbuf);
        gemm_kernel<<<dim3(2, 16), 256, 0, stream>>>(h, kvaT + (size_t)l * 768 * 256, 768, 256,
            kva_b + l * 256, nullptr, 0, nullptr, lat);
        gemm_kernel<<<dim3(12, 16), 256, 0, stream>>>(lat, kvbT + (size_t)l * 256 * 1536, 256, 1536,
            kvb_b + l * 1536, nullptr, 0, nullptr, kvbuf);
        rope_apply_kernel<<<3072, 256, 0, stream>>>(qbuf, 768, cosT, sinT);
        rope_apply_kernel<<<3072, 256, 0, stream>>>(kvbuf, 1536, cosT, sinT);
        attn_kernel<<<dim3(64, 24), 256, 0, stream>>>(qbuf, kvbuf, attnb);
        gemm_kernel<<<dim3(6, 16), 256, 0, stream>>>(attnb, outT + (size_t)l * 768 * 768, 768, 768,
            out_b + l * 768, x, 0, x, nullptr);
        ln_kernel<<<2048, 256, 0, stream>>>(x, ln2_w + l * 768, ln2_b + l * 768, h);
        gemm_kernel<<<dim3(24, 16), 256, 0, stream>>>(h, fcT + (size_t)l * 768 * 3072, 768, 3072,
            fc_b + l * 3072, nullptr, 1, nullptr, fca);
        gemm_kernel<<<dim3(6, 16), 256, 0, stream>>>(fca, projT + (size_t)l * 3072 * 768, 3072, 768,
            proj_b + l * 768, x, 0, x, nullptr);
    }
    ln_kernel<<<2048, 256, 0, stream>>>(x, lnf_w, lnf_b, h);
    gemm_kernel<<<dim3(393, 16), 256, 0, stream>>>(h, wteB, 768, 50257,
        nullptr, nullptr, 0, (float*)d_out, nullptr);
}

// Round 2
// 5147.750 us; speedup vs baseline: 1.2765x; 1.2765x over previous
//
#include <hip/hip_runtime.h>
#include <cstdint>
#include <cstddef>

// GPT2-MLA forward, MI355X. Round 1: dbuf-prefetch GEMM w/ XOR-swizzled LDS,
// 64x128 tiles (M-fastest grid), fused wq|kva dispatch.
// B=2, T=1024, D=768, L=12, H=12, HD=64, DL=256, V=50257 (pad 50304)

typedef unsigned short ushortT;
typedef __bf16 bf16x8 __attribute__((ext_vector_type(8)));
typedef float f32x4 __attribute__((ext_vector_type(4)));
typedef unsigned short us8 __attribute__((ext_vector_type(8)));

#define NHEAD 12
#define T_SEQ 1024

__device__ __forceinline__ float bf2f(unsigned short u) {
    union { unsigned int i; float f; } v; v.i = ((unsigned int)u) << 16; return v.f;
}
__device__ __forceinline__ unsigned short f2bf(float f) {
    union { float f; unsigned int i; } v; v.f = f;
    unsigned int r = v.i + 0x7fffu + ((v.i >> 16) & 1u);
    return (unsigned short)(r >> 16);
}
__device__ __forceinline__ float readlane_f(float v, int l) {
    return __uint_as_float(__builtin_amdgcn_readlane(__float_as_uint(v), l));
}
__device__ __forceinline__ void gload_lds16(const void* g, void* l) {
    __builtin_amdgcn_global_load_lds((__attribute__((address_space(1))) void*)g,
                                     (__attribute__((address_space(3))) void*)l, 16, 0, 0);
}

// ---------------- weight convert / transpose ----------------
// in: f32 [L][K][N] -> out rows (outRowOff+n), layer stride outLS, row len K
__global__ void transpose_cvt_kernel(const float* __restrict__ in, ushortT* __restrict__ outp,
                                     int K, int N, int outRowOff, size_t outLS) {
    __shared__ float tile[32][33];
    const int tx = threadIdx.x, ty = threadIdx.y;
    const int n0 = blockIdx.x * 32, k0 = blockIdx.y * 32;
    const float* src = in + (size_t)blockIdx.z * K * N;
#pragma unroll
    for (int j = 0; j < 4; ++j)
        tile[ty + j * 8][tx] = src[(size_t)(k0 + ty + j * 8) * N + n0 + tx];
    __syncthreads();
    ushortT* dst = outp + (size_t)blockIdx.z * outLS;
#pragma unroll
    for (int j = 0; j < 4; ++j)
        dst[(size_t)(outRowOff + n0 + ty + j * 8) * K + k0 + tx] = f2bf(tile[tx][ty + j * 8]);
}

// wte f32 [50257*768] -> bf16 [50304*768] zero-padded
__global__ void cvt_wte_kernel(const float* __restrict__ in, ushortT* __restrict__ outp) {
    size_t i4 = (size_t)blockIdx.x * 256 + threadIdx.x;
    ushort4 o;
    if (i4 < 9649344) {
        float4 v = ((const float4*)in)[i4];
        o.x = f2bf(v.x); o.y = f2bf(v.y); o.z = f2bf(v.z); o.w = f2bf(v.w);
    } else { o.x = 0; o.y = 0; o.z = 0; o.w = 0; }
    ((ushort4*)outp)[i4] = o;
}

// ---------------- embedding ----------------
__global__ void embed_kernel(const int* __restrict__ idx, const float* __restrict__ wte,
                             const float* __restrict__ wpe, float* __restrict__ x) {
    int i = blockIdx.x * 256 + threadIdx.x;
    int row = i / 768, d = i - row * 768;
    int t = row & 1023;
    x[i] = wte[(size_t)idx[row] * 768 + d] + wpe[(size_t)t * 768 + d];
}

// ---------------- rope ----------------
__global__ void rope_tables_kernel(float* __restrict__ cosT, float* __restrict__ sinT) {
    int i = blockIdx.x * 256 + threadIdx.x;  // 1024*32
    int t = i >> 5, f = i & 31;
    float invf = exp2f(-(float)f * (13.287712379549449f / 32.0f));
    float ang = (float)t * invf;
    cosT[i] = cosf(ang);
    sinT[i] = sinf(ang);
}

__global__ void rope_apply_kernel(ushortT* __restrict__ x, int stride,
                                  const float* __restrict__ cosT, const float* __restrict__ sinT) {
    int i = blockIdx.x * 256 + threadIdx.x;  // 2048*12*32
    int row = i / 384, r = i - row * 384;
    int h = r >> 5, f = r & 31;
    int t = row & 1023;
    size_t base = (size_t)row * stride + h * 64 + f;
    float x1 = bf2f(x[base]), x2 = bf2f(x[base + 32]);
    float c = cosT[t * 32 + f], s = sinT[t * 32 + f];
    x[base] = f2bf(x1 * c - x2 * s);
    x[base + 32] = f2bf(x2 * c + x1 * s);
}

// ---------------- layernorm ----------------
__global__ __launch_bounds__(256) void ln_kernel(const float* __restrict__ x,
                                                 const float* __restrict__ wg,
                                                 const float* __restrict__ bg,
                                                 ushortT* __restrict__ outp) {
    const int row = blockIdx.x, tid = threadIdx.x;
    const float* xr = x + (size_t)row * 768;
    float v0 = xr[tid], v1 = xr[tid + 256], v2 = xr[tid + 512];
    float s = v0 + v1 + v2;
    float ss = v0 * v0 + v1 * v1 + v2 * v2;
#pragma unroll
    for (int off = 32; off >= 1; off >>= 1) {
        s += __shfl_xor(s, off);
        ss += __shfl_xor(ss, off);
    }
    __shared__ float sb[4], ssb[4];
    if ((tid & 63) == 0) { sb[tid >> 6] = s; ssb[tid >> 6] = ss; }
    __syncthreads();
    float S = sb[0] + sb[1] + sb[2] + sb[3];
    float SS = ssb[0] + ssb[1] + ssb[2] + ssb[3];
    const float mean = S * (1.0f / 768.0f);
    float var = SS * (1.0f / 768.0f) - mean * mean;
    const float rs = rsqrtf(var + 1e-5f);
    ushortT* orow = outp + (size_t)row * 768;
    orow[tid]       = f2bf((v0 - mean) * rs * wg[tid]       + bg[tid]);
    orow[tid + 256] = f2bf((v1 - mean) * rs * wg[tid + 256] + bg[tid + 256]);
    orow[tid + 512] = f2bf((v2 - mean) * rs * wg[tid + 512] + bg[tid + 512]);
}

// ---------------- GEMM: C[2048 x N] = A[2048 x K] @ Bt[N x K]^T (bf16 MFMA) ----------
// BM=64 BN=128 BK=64, 256thr/4 waves (each 32x64). LDS double-buffered, XOR-swizzled
// (slot = chunk ^ (row&7), applied on global src + read addr; gload_lds dest linear).
// Single barrier per K-step: prefetch t+1 issued before compute of t (T3 minimum).
// grid = (M/64, N/128): M fastest -> consecutive blocks share B panel (L2-hot).
__global__ __launch_bounds__(256) void gemm64_kernel(
    const ushortT* __restrict__ A, int lda,
    const ushortT* __restrict__ Bt, int ldb,
    int K, int CS, int Nstore,
    const float* __restrict__ bias0, const float* __restrict__ bias1,
    ushortT* __restrict__ outB0, int ld0,
    ushortT* __restrict__ outB1, int ld1,
    const float* __restrict__ resid, float* __restrict__ outF, int ldF,
    int act) {
    __shared__ __align__(16) char lds[49152];  // As[2][8192] + Bs[2][16384]
    char* AsB = lds;
    char* BsB = lds + 16384;
    const int tid = threadIdx.x;
    const int w = tid >> 6, lane = tid & 63;
    const int m0 = blockIdx.x * 64, n0 = blockIdx.y * 128;
    const int fr = lane & 15, kg = lane >> 4;
    const int wm = w >> 1, wn = w & 1;
    const int l8 = lane >> 3;
    const int cgo = (((lane & 7) ^ l8) << 4);  // pre-swizzled source chunk byte off
    const size_t ldaB = (size_t)lda * 2, ldbB = (size_t)ldb * 2;
    const char* Ab = (const char*)A;
    const char* Bb = (const char*)Bt;
    f32x4 acc[2][4] = {};

    auto stage = [&](int buf, int t) {
        const size_t ktB = (size_t)t << 7;
        char* As_ = AsB + (buf << 13);
        char* Bs_ = BsB + (buf << 14);
#pragma unroll
        for (int i = 0; i < 2; ++i) {
            const int sg = w * 2 + i;
            gload_lds16(Ab + (size_t)(m0 + sg * 8 + l8) * ldaB + ktB + cgo, As_ + sg * 1024);
        }
#pragma unroll
        for (int i = 0; i < 4; ++i) {
            const int sg = w * 4 + i;
            gload_lds16(Bb + (size_t)(n0 + sg * 8 + l8) * ldbB + ktB + cgo, Bs_ + sg * 1024);
        }
    };

    stage(0, 0);
    const int nk = K >> 6;
    __syncthreads();
    const int fr7 = fr & 7;
    const int sk0 = ((kg + 0) ^ fr7) << 4;  // ks=0 swizzled slot byte off
    const int sk1 = ((kg + 4) ^ fr7) << 4;  // ks=1
    for (int t = 0; t < nk; ++t) {
        const int cur = t & 1;
        if (t + 1 < nk) stage(cur ^ 1, t + 1);
        const char* As_ = AsB + (cur << 13);
        const char* Bs_ = BsB + (cur << 14);
        bf16x8 af[2][2], bfr[4][2];
#pragma unroll
        for (int mf = 0; mf < 2; ++mf) {
            const int rb = (wm * 32 + mf * 16 + fr) << 7;
            af[mf][0] = *(const bf16x8*)(As_ + rb + sk0);
            af[mf][1] = *(const bf16x8*)(As_ + rb + sk1);
        }
#pragma unroll
        for (int nf = 0; nf < 4; ++nf) {
            const int rb = (wn * 64 + nf * 16 + fr) << 7;
            bfr[nf][0] = *(const bf16x8*)(Bs_ + rb + sk0);
            bfr[nf][1] = *(const bf16x8*)(Bs_ + rb + sk1);
        }
#pragma unroll
        for (int ks = 0; ks < 2; ++ks)
#pragma unroll
            for (int mf = 0; mf < 2; ++mf)
#pragma unroll
                for (int nf = 0; nf < 4; ++nf)
                    acc[mf][nf] = __builtin_amdgcn_mfma_f32_16x16x32_bf16(
                        af[mf][ks], bfr[nf][ks], acc[mf][nf], 0, 0, 0);
        __syncthreads();
    }

    // epilogue: C row = kg*4+j, col = fr within each 16x16 frag
#pragma unroll
    for (int mf = 0; mf < 2; ++mf) {
#pragma unroll
        for (int nf = 0; nf < 4; ++nf) {
            const int gcol = n0 + wn * 64 + nf * 16 + fr;
            if (gcol >= Nstore) continue;
            float bv = 0.0f;
            if (gcol < CS) { if (bias0) bv = bias0[gcol]; }
            else           { if (bias1) bv = bias1[gcol - CS]; }
#pragma unroll
            for (int j = 0; j < 4; ++j) {
                const int grow = m0 + wm * 32 + mf * 16 + kg * 4 + j;
                float v = acc[mf][nf][j] + bv;
                if (resid) v += resid[(size_t)grow * ldF + gcol];
                if (act) v = 0.5f * v * (1.0f + erff(v * 0.70710678118654752f));
                if (outF) outF[(size_t)grow * ldF + gcol] = v;
                if (gcol < CS) {
                    if (outB0) outB0[(size_t)grow * ld0 + gcol] = f2bf(v);
                } else {
                    if (outB1) outB1[(size_t)grow * ld1 + gcol - CS] = f2bf(v);
                }
            }
        }
    }
}

// ---------------- attention (unchanged round-0 VALU version) ----------------
__global__ __launch_bounds__(256) void attn_kernel(const ushortT* __restrict__ q,
                                                   const ushortT* __restrict__ kv,
                                                   ushortT* __restrict__ attnb) {
    __shared__ float ks[64][65];
    const int tid = threadIdx.x, w = tid >> 6, lane = tid & 63;
    const int qb = blockIdx.x * 16;
    const int b = blockIdx.y / NHEAD, h = blockIdx.y % NHEAD;
    const int t0 = qb + w * 4;
    const size_t qrow0 = (size_t)b * T_SEQ + t0;

    float qreg[4];
#pragma unroll
    for (int r = 0; r < 4; ++r)
        qreg[r] = bf2f(q[(qrow0 + r) * 768 + h * 64 + lane]);

    float p[4][16];
#pragma unroll
    for (int r = 0; r < 4; ++r)
#pragma unroll
        for (int c = 0; c < 16; ++c) p[r][c] = -1e30f;

    const int nc = (qb >> 6) + 1;
    const ushortT* kbase = kv + (size_t)b * T_SEQ * 1536 + h * 64;
    const ushortT* vbase = kbase + 768;
    const int rr = tid >> 2, dg = tid & 3;

#pragma unroll
    for (int c = 0; c < 16; ++c) {
        if (c >= nc) break;
        __syncthreads();
        {
            const ushortT* src = kbase + (size_t)(c * 64 + rr) * 1536 + dg * 16;
            us8 u0 = *(const us8*)src, u1 = *(const us8*)(src + 8);
#pragma unroll
            for (int j = 0; j < 8; ++j) {
                ks[rr][dg * 16 + j] = bf2f(u0[j]);
                ks[rr][dg * 16 + 8 + j] = bf2f(u1[j]);
            }
        }
        __syncthreads();
        const int s = c * 64 + lane;
        float a0 = 0.f, a1 = 0.f, a2 = 0.f, a3 = 0.f;
#pragma unroll
        for (int d = 0; d < 64; ++d) {
            const float kd = ks[lane][d];
            a0 += readlane_f(qreg[0], d) * kd;
            a1 += readlane_f(qreg[1], d) * kd;
            a2 += readlane_f(qreg[2], d) * kd;
            a3 += readlane_f(qreg[3], d) * kd;
        }
        if (s <= t0)     p[0][c] = a0 * 0.125f;
        if (s <= t0 + 1) p[1][c] = a1 * 0.125f;
        if (s <= t0 + 2) p[2][c] = a2 * 0.125f;
        if (s <= t0 + 3) p[3][c] = a3 * 0.125f;
    }

    float li[4];
#pragma unroll
    for (int r = 0; r < 4; ++r) {
        float mm = -1e30f;
#pragma unroll
        for (int c = 0; c < 16; ++c) mm = fmaxf(mm, p[r][c]);
#pragma unroll
        for (int off = 32; off >= 1; off >>= 1) mm = fmaxf(mm, __shfl_xor(mm, off));
        float ll = 0.f;
#pragma unroll
        for (int c = 0; c < 16; ++c) {
            float e = __expf(p[r][c] - mm);
            p[r][c] = e;
            ll += e;
        }
#pragma unroll
        for (int off = 32; off >= 1; off >>= 1) ll += __shfl_xor(ll, off);
        li[r] = 1.0f / ll;
    }

    float o[4] = {0.f, 0.f, 0.f, 0.f};
#pragma unroll
    for (int c = 0; c < 16; ++c) {
        if (c >= nc) break;
        __syncthreads();
        {
            const ushortT* src = vbase + (size_t)(c * 64 + rr) * 1536 + dg * 16;
            us8 u0 = *(const us8*)src, u1 = *(const us8*)(src + 8);
#pragma unroll
            for (int j = 0; j < 8; ++j) {
                ks[rr][dg * 16 + j] = bf2f(u0[j]);
                ks[rr][dg * 16 + 8 + j] = bf2f(u1[j]);
            }
        }
        __syncthreads();
#pragma unroll
        for (int sl = 0; sl < 64; ++sl) {
            const float vv = ks[sl][lane];
            o[0] += readlane_f(p[0][c], sl) * vv;
            o[1] += readlane_f(p[1][c], sl) * vv;
            o[2] += readlane_f(p[2][c], sl) * vv;
            o[3] += readlane_f(p[3][c], sl) * vv;
        }
    }
#pragma unroll
    for (int r = 0; r < 4; ++r)
        attnb[(qrow0 + r) * 768 + h * 64 + lane] = f2bf(o[r] * li[r]);
}

// ---------------- host ----------------
extern "C" void kernel_launch(void* const* d_in, const int* in_sizes, int n_in,
                              void* d_out, int out_size, void* d_ws, size_t ws_size,
                              hipStream_t stream) {
    (void)in_sizes; (void)n_in; (void)out_size; (void)ws_size;
    const int*   idxp   = (const int*)d_in[0];
    const float* wte    = (const float*)d_in[1];
    const float* wpe    = (const float*)d_in[2];
    const float* ln1_w  = (const float*)d_in[3];
    const float* ln1_b  = (const float*)d_in[4];
    const float* wq_w   = (const float*)d_in[5];
    const float* wq_b   = (const float*)d_in[6];
    const float* kva_w  = (const float*)d_in[7];
    const float* kva_b  = (const float*)d_in[8];
    const float* kvb_w  = (const float*)d_in[9];
    const float* kvb_b  = (const float*)d_in[10];
    const float* out_w  = (const float*)d_in[11];
    const float* out_b  = (const float*)d_in[12];
    const float* ln2_w  = (const float*)d_in[13];
    const float* ln2_b  = (const float*)d_in[14];
    const float* fc_w   = (const float*)d_in[15];
    const float* fc_b   = (const float*)d_in[16];
    const float* proj_w = (const float*)d_in[17];
    const float* proj_b = (const float*)d_in[18];
    const float* lnf_w  = (const float*)d_in[19];
    const float* lnf_b  = (const float*)d_in[20];

    char* ws = (char*)d_ws;
    size_t off = 0;
    auto alloc = [&](size_t bytes) -> char* {
        char* p = ws + off;
        off += (bytes + 255) & ~(size_t)255;
        return p;
    };
    ushortT* wqkvaT = (ushortT*)alloc((size_t)12 * 1024 * 768 * 2);  // [wq rows 0..767 | kva rows 768..1023][768]
    ushortT* kvbT   = (ushortT*)alloc((size_t)12 * 1536 * 256 * 2);
    ushortT* outT   = (ushortT*)alloc((size_t)12 * 768 * 768 * 2);
    ushortT* fcT    = (ushortT*)alloc((size_t)12 * 3072 * 768 * 2);
    ushortT* projT  = (ushortT*)alloc((size_t)12 * 768 * 3072 * 2);
    ushortT* wteB   = (ushortT*)alloc((size_t)50304 * 768 * 2);
    float* cosT = (float*)alloc((size_t)1024 * 32 * 4);
    float* sinT = (float*)alloc((size_t)1024 * 32 * 4);
    float*   x     = (float*)alloc((size_t)2048 * 768 * 4);
    ushortT* h     = (ushortT*)alloc((size_t)2048 * 768 * 2);
    ushortT* qbuf  = (ushortT*)alloc((size_t)2048 * 768 * 2);
    ushortT* lat   = (ushortT*)alloc((size_t)2048 * 256 * 2);
    ushortT* kvbuf = (ushortT*)alloc((size_t)2048 * 1536 * 2);
    ushortT* attnb = (ushortT*)alloc((size_t)2048 * 768 * 2);
    ushortT* fca   = (ushortT*)alloc((size_t)2048 * 3072 * 2);

    const dim3 blkT(32, 8);
    transpose_cvt_kernel<<<dim3(24, 24, 12), blkT, 0, stream>>>(wq_w,  wqkvaT, 768, 768,  0,   (size_t)1024 * 768);
    transpose_cvt_kernel<<<dim3(8,  24, 12), blkT, 0, stream>>>(kva_w, wqkvaT, 768, 256,  768, (size_t)1024 * 768);
    transpose_cvt_kernel<<<dim3(48, 8,  12), blkT, 0, stream>>>(kvb_w, kvbT,   256, 1536, 0,   (size_t)1536 * 256);
    transpose_cvt_kernel<<<dim3(24, 24, 12), blkT, 0, stream>>>(out_w, outT,   768, 768,  0,   (size_t)768 * 768);
    transpose_cvt_kernel<<<dim3(96, 24, 12), blkT, 0, stream>>>(fc_w,  fcT,    768, 3072, 0,   (size_t)3072 * 768);
    transpose_cvt_kernel<<<dim3(24, 96, 12), blkT, 0, stream>>>(proj_w, projT, 3072, 768, 0,   (size_t)768 * 3072);
    cvt_wte_kernel<<<37728, 256, 0, stream>>>(wte, wteB);
    rope_tables_kernel<<<128, 256, 0, stream>>>(cosT, sinT);
    embed_kernel<<<6144, 256, 0, stream>>>(idxp, wte, wpe, x);

    for (int l = 0; l < 12; ++l) {
        ln_kernel<<<2048, 256, 0, stream>>>(x, ln1_w + l * 768, ln1_b + l * 768, h);
        // fused q | kv_latent GEMM: N = 768 + 256
        gemm64_kernel<<<dim3(32, 8), 256, 0, stream>>>(
            h, 768, wqkvaT + (size_t)l * 1024 * 768, 768, 768,
            768, 1024, wq_b + l * 768, kva_b + l * 256,
            qbuf, 768, lat, 256, nullptr, nullptr, 0, 0);
        gemm64_kernel<<<dim3(32, 12), 256, 0, stream>>>(
            lat, 256, kvbT + (size_t)l * 1536 * 256, 256, 256,
            1536, 1536, kvb_b + l * 1536, nullptr,
            kvbuf, 1536, nullptr, 0, nullptr, nullptr, 0, 0);
        rope_apply_kernel<<<3072, 256, 0, stream>>>(qbuf, 768, cosT, sinT);
        rope_apply_kernel<<<3072, 256, 0, stream>>>(kvbuf, 1536, cosT, sinT);
        attn_kernel<<<dim3(64, 24), 256, 0, stream>>>(qbuf, kvbuf, attnb);
        gemm64_kernel<<<dim3(32, 6), 256, 0, stream>>>(
            attnb, 768, outT + (size_t)l * 768 * 768, 768, 768,
            768, 768, out_b + l * 768, nullptr,
            nullptr, 0, nullptr, 0, x, x, 768, 0);
        ln_kernel<<<2048, 256, 0, stream>>>(x, ln2_w + l * 768, ln2_b + l * 768, h);
        gemm64_kernel<<<dim3(32, 24), 256, 0, stream>>>(
            h, 768, fcT + (size_t)l * 3072 * 768, 768, 768,
            3072, 3072, fc_b + l * 3072, nullptr,
            fca, 3072, nullptr, 0, nullptr, nullptr, 0, 1);
        gemm64_kernel<<<dim3(32, 6), 256, 0, stream>>>(
            fca, 3072, projT + (size_t)l * 768 * 3072, 3072, 3072,
            768, 768, proj_b + l * 768, nullptr,
            nullptr, 0, nullptr, 0, x, x, 768, 0);
    }
    ln_kernel<<<2048, 256, 0, stream>>>(x, lnf_w, lnf_b, h);
    gemm64_kernel<<<dim3(32, 393), 256, 0, stream>>>(
        h, 768, wteB, 768, 768,
        50304, 50257, nullptr, nullptr,
        nullptr, 0, nullptr, 0, nullptr, (float*)d_out, 50257, 0);
}

// Round 3
// 2717.617 us; speedup vs baseline: 2.4180x; 1.8942x over previous
//
#include <hip/hip_runtime.h>
#include <cstdint>
#include <cstddef>

// GPT2-MLA forward, MI355X. Round 3: MFMA flash-attention (S^T trick, V^T path),
// BM=128 dbuf-swizzled GEMM (BN templated 128/64), fused rope dispatch.
// B=2, T=1024, D=768, L=12, H=12, HD=64, DL=256, V=50257 (pad 50304)

typedef unsigned short ushortT;
typedef __bf16 bf16x8 __attribute__((ext_vector_type(8)));
typedef float f32x4 __attribute__((ext_vector_type(4)));
typedef unsigned short us8 __attribute__((ext_vector_type(8)));

#define NHEAD 12
#define T_SEQ 1024

__device__ __forceinline__ float bf2f(unsigned short u) {
    union { unsigned int i; float f; } v; v.i = ((unsigned int)u) << 16; return v.f;
}
__device__ __forceinline__ unsigned short f2bf(float f) {
    union { float f; unsigned int i; } v; v.f = f;
    unsigned int r = v.i + 0x7fffu + ((v.i >> 16) & 1u);
    return (unsigned short)(r >> 16);
}
__device__ __forceinline__ unsigned int pack2(float a, float b) {
    return (unsigned int)f2bf(a) | ((unsigned int)f2bf(b) << 16);
}
__device__ __forceinline__ void gload_lds16(const void* g, void* l) {
    __builtin_amdgcn_global_load_lds((__attribute__((address_space(1))) void*)g,
                                     (__attribute__((address_space(3))) void*)l, 16, 0, 0);
}

// ---------------- weight convert / transpose ----------------
__global__ void transpose_cvt_kernel(const float* __restrict__ in, ushortT* __restrict__ outp,
                                     int K, int N, int outRowOff, size_t outLS) {
    __shared__ float tile[32][33];
    const int tx = threadIdx.x, ty = threadIdx.y;
    const int n0 = blockIdx.x * 32, k0 = blockIdx.y * 32;
    const float* src = in + (size_t)blockIdx.z * K * N;
#pragma unroll
    for (int j = 0; j < 4; ++j)
        tile[ty + j * 8][tx] = src[(size_t)(k0 + ty + j * 8) * N + n0 + tx];
    __syncthreads();
    ushortT* dst = outp + (size_t)blockIdx.z * outLS;
#pragma unroll
    for (int j = 0; j < 4; ++j)
        dst[(size_t)(outRowOff + n0 + ty + j * 8) * K + k0 + tx] = f2bf(tile[tx][ty + j * 8]);
}

__global__ void cvt_wte_kernel(const float* __restrict__ in, ushortT* __restrict__ outp) {
    size_t i4 = (size_t)blockIdx.x * 256 + threadIdx.x;
    ushort4 o;
    if (i4 < 9649344) {
        float4 v = ((const float4*)in)[i4];
        o.x = f2bf(v.x); o.y = f2bf(v.y); o.z = f2bf(v.z); o.w = f2bf(v.w);
    } else { o.x = 0; o.y = 0; o.z = 0; o.w = 0; }
    ((ushort4*)outp)[i4] = o;
}

// ---------------- embedding ----------------
__global__ void embed_kernel(const int* __restrict__ idx, const float* __restrict__ wte,
                             const float* __restrict__ wpe, float* __restrict__ x) {
    int i = blockIdx.x * 256 + threadIdx.x;
    int row = i / 768, d = i - row * 768;
    int t = row & 1023;
    x[i] = wte[(size_t)idx[row] * 768 + d] + wpe[(size_t)t * 768 + d];
}

// ---------------- rope ----------------
__global__ void rope_tables_kernel(float* __restrict__ cosT, float* __restrict__ sinT) {
    int i = blockIdx.x * 256 + threadIdx.x;  // 1024*32
    int t = i >> 5, f = i & 31;
    float invf = exp2f(-(float)f * (13.287712379549449f / 32.0f));
    float ang = (float)t * invf;
    cosT[i] = cosf(ang);
    sinT[i] = sinf(ang);
}

// fused: applies rope to qbuf rows [2048][768] and kbuf rows [2048][768]
__global__ void rope_apply2_kernel(ushortT* __restrict__ qb_, ushortT* __restrict__ kb_,
                                   const float* __restrict__ cosT, const float* __restrict__ sinT) {
    int i = blockIdx.x * 256 + threadIdx.x;  // 2 * 2048*384
    int which = (i >= 786432);
    int ii = i - which * 786432;
    ushortT* x = which ? kb_ : qb_;
    int row = ii / 384, r = ii - row * 384;
    int h = r >> 5, f = r & 31;
    int t = row & 1023;
    size_t base = (size_t)row * 768 + h * 64 + f;
    float x1 = bf2f(x[base]), x2 = bf2f(x[base + 32]);
    float c = cosT[t * 32 + f], s = sinT[t * 32 + f];
    x[base] = f2bf(x1 * c - x2 * s);
    x[base + 32] = f2bf(x2 * c + x1 * s);
}

// ---------------- layernorm ----------------
__global__ __launch_bounds__(256) void ln_kernel(const float* __restrict__ x,
                                                 const float* __restrict__ wg,
                                                 const float* __restrict__ bg,
                                                 ushortT* __restrict__ outp) {
    const int row = blockIdx.x, tid = threadIdx.x;
    const float* xr = x + (size_t)row * 768;
    float v0 = xr[tid], v1 = xr[tid + 256], v2 = xr[tid + 512];
    float s = v0 + v1 + v2;
    float ss = v0 * v0 + v1 * v1 + v2 * v2;
#pragma unroll
    for (int off = 32; off >= 1; off >>= 1) {
        s += __shfl_xor(s, off);
        ss += __shfl_xor(ss, off);
    }
    __shared__ float sb[4], ssb[4];
    if ((tid & 63) == 0) { sb[tid >> 6] = s; ssb[tid >> 6] = ss; }
    __syncthreads();
    float S = sb[0] + sb[1] + sb[2] + sb[3];
    float SS = ssb[0] + ssb[1] + ssb[2] + ssb[3];
    const float mean = S * (1.0f / 768.0f);
    float var = SS * (1.0f / 768.0f) - mean * mean;
    const float rs = rsqrtf(var + 1e-5f);
    ushortT* orow = outp + (size_t)row * 768;
    orow[tid]       = f2bf((v0 - mean) * rs * wg[tid]       + bg[tid]);
    orow[tid + 256] = f2bf((v1 - mean) * rs * wg[tid + 256] + bg[tid + 256]);
    orow[tid + 512] = f2bf((v2 - mean) * rs * wg[tid + 512] + bg[tid + 512]);
}

// ---------------- GEMM: C[2048 x N] = A[2048 x K] @ Bt[N x K]^T ----------------
// BM=128, BN=NF*16, BK=64. 4 waves stacked in M (32 rows each), nf=NF frags wide.
// LDS double-buffered + XOR swizzle (chunk^(row&7), both sides). One barrier/K-step.
// mode1: 0 = outB1 row-major [2048][ld1]; 1 = outB1 is vT[b][h][d][t] transposed.
template<int NF>
__global__ __launch_bounds__(256) void gemm128(
    const ushortT* __restrict__ A, int lda,
    const ushortT* __restrict__ Bt, int ldb,
    int K, int CS, int Nstore,
    const float* __restrict__ bias0, const float* __restrict__ bias1,
    ushortT* __restrict__ outB0, int ld0,
    ushortT* __restrict__ outB1, int ld1, int mode1,
    const float* __restrict__ resid, float* __restrict__ outF, int ldF,
    int act) {
    __shared__ __align__(16) char lds[32768 + NF * 4096];
    char* AsB = lds;
    char* BsB = lds + 32768;
    const int tid = threadIdx.x;
    const int w = tid >> 6, lane = tid & 63;
    const int m0 = blockIdx.x * 128, n0 = blockIdx.y * NF * 16;
    const int fr = lane & 15, kg = lane >> 4;
    const size_t ldaB = (size_t)lda * 2, ldbB = (size_t)ldb * 2;
    const char* Ab = (const char*)A;
    const char* Bb = (const char*)Bt;
    f32x4 acc[2][NF] = {};

    auto stage = [&](int buf, int t) {
        const size_t ktB = (size_t)t << 7;
        char* As_ = AsB + buf * 16384;
        char* Bs_ = BsB + buf * NF * 2048;
#pragma unroll
        for (int jj = 0; jj < 4; ++jj) {
            const int i = tid + jj * 256;
            const int r = i >> 3, c = i & 7, cc = c ^ (r & 7);
            gload_lds16(Ab + (size_t)(m0 + r) * ldaB + ktB + cc * 16, As_ + i * 16);
        }
#pragma unroll
        for (int jj = 0; jj < NF / 2; ++jj) {
            const int i = tid + jj * 256;
            const int r = i >> 3, c = i & 7, cc = c ^ (r & 7);
            gload_lds16(Bb + (size_t)(n0 + r) * ldbB + ktB + cc * 16, Bs_ + i * 16);
        }
    };

    stage(0, 0);
    const int nk = K >> 6;
    __syncthreads();
    for (int t = 0; t < nk; ++t) {
        const int cur = t & 1;
        if (t + 1 < nk) stage(cur ^ 1, t + 1);
        const char* As_ = AsB + cur * 16384;
        const char* Bs_ = BsB + cur * NF * 2048;
#pragma unroll
        for (int ks = 0; ks < 2; ++ks) {
            bf16x8 af[2];
#pragma unroll
            for (int mf = 0; mf < 2; ++mf) {
                const int row = w * 32 + mf * 16 + fr;
                af[mf] = *(const bf16x8*)(As_ + row * 128 + (((ks * 4 + kg) ^ (row & 7)) << 4));
            }
#pragma unroll
            for (int nf = 0; nf < NF; ++nf) {
                const int row = nf * 16 + fr;
                bf16x8 bfrag = *(const bf16x8*)(Bs_ + row * 128 + (((ks * 4 + kg) ^ (row & 7)) << 4));
#pragma unroll
                for (int mf = 0; mf < 2; ++mf)
                    acc[mf][nf] = __builtin_amdgcn_mfma_f32_16x16x32_bf16(
                        af[mf], bfrag, acc[mf][nf], 0, 0, 0);
            }
        }
        __syncthreads();
    }

    // epilogue: frag row = kg*4+j, col = fr
#pragma unroll
    for (int mf = 0; mf < 2; ++mf) {
#pragma unroll
        for (int nf = 0; nf < NF; ++nf) {
            const int gcol = n0 + nf * 16 + fr;
            if (gcol >= Nstore) continue;
            float bv = 0.0f;
            if (gcol < CS) { if (bias0) bv = bias0[gcol]; }
            else           { if (bias1) bv = bias1[gcol - CS]; }
#pragma unroll
            for (int j = 0; j < 4; ++j) {
                const int grow = m0 + w * 32 + mf * 16 + kg * 4 + j;
                float v = acc[mf][nf][j] + bv;
                if (resid) v += resid[(size_t)grow * ldF + gcol];
                if (act) v = 0.5f * v * (1.0f + erff(v * 0.70710678118654752f));
                if (outF) outF[(size_t)grow * ldF + gcol] = v;
                if (gcol < CS) {
                    if (outB0) outB0[(size_t)grow * ld0 + gcol] = f2bf(v);
                } else if (outB1) {
                    if (mode1 == 0) {
                        outB1[(size_t)grow * ld1 + gcol - CS] = f2bf(v);
                    } else {
                        // vT[b][h][d][t]
                        const int bb = grow >> 10, tt = grow & 1023;
                        const int hd = gcol - CS;
                        outB1[((size_t)((bb * 12 + (hd >> 6)) * 64 + (hd & 63)) << 10) + tt] = f2bf(v);
                    }
                }
            }
        }
    }
}

// ---------------- MFMA flash attention ----------------
// Grid (16, 24): x = q-tile of 64 rows, y = (b,h). 4 waves, wave w owns 16 q rows.
// S^T = mfma(Kfrag, Qfrag) -> lane (fr,kg) holds q-row fr's scores (s = n*16+kg*4+j).
// Online softmax per-lane; P exchanged via per-wave LDS row buffer; PV = mfma(P, V^T).
__global__ __launch_bounds__(256) void attn_mfma(const ushortT* __restrict__ q,
                                                 const ushortT* __restrict__ kbuf,
                                                 const ushortT* __restrict__ vT,
                                                 ushortT* __restrict__ attnb) {
    __shared__ __align__(16) char lds[41472];  // K dbuf 16K | V dbuf 16K | P 4x2176
    const int tid = threadIdx.x, w = tid >> 6, lane = tid & 63;
    const int fr = lane & 15, kg = lane >> 4;
    const int b = blockIdx.y / NHEAD, h = blockIdx.y % NHEAD;
    const int qb = blockIdx.x * 64;
    const int q0 = qb + w * 16;
    const int nst = (qb >> 6) + 1, diag = qb >> 6;

    const ushortT* qrow = q + ((size_t)(b * 1024 + q0 + fr) * 768 + h * 64);
    const bf16x8 qf0 = *(const bf16x8*)(qrow + kg * 8);
    const bf16x8 qf1 = *(const bf16x8*)(qrow + 32 + kg * 8);

    const char* kgb = (const char*)kbuf + ((size_t)(b * 1024) * 768 + h * 64) * 2;
    const char* vgb = (const char*)vT + ((size_t)(b * 12 + h) * 65536) * 2;
    char* Pw = lds + 32768 + w * 2176 + fr * 136;

    auto stage = [&](int buf, int st) {
#pragma unroll
        for (int jj = 0; jj < 2; ++jj) {
            const int i = tid + jj * 256;
            const int r = i >> 3, c = i & 7, cc = c ^ (r & 7);
            gload_lds16(kgb + (size_t)(st * 64 + r) * 1536 + cc * 16, lds + buf * 8192 + i * 16);
            gload_lds16(vgb + (size_t)r * 2048 + st * 128 + cc * 16, lds + 16384 + buf * 8192 + i * 16);
        }
    };

    float m_r = -1e30f, l_r = 0.0f;
    f32x4 o[4] = {};

    stage(0, 0);
    __syncthreads();
    for (int st = 0; st < nst; ++st) {
        const int cur = st & 1;
        if (st + 1 < nst) stage(cur ^ 1, st + 1);
        const char* Kd = lds + cur * 8192;
        const char* Vd = lds + 16384 + cur * 8192;

        // S^T frags: sfr[n] rows s = n*16+kg*4+j, col q=fr
        f32x4 sfr[4];
#pragma unroll
        for (int n = 0; n < 4; ++n) {
            const int row = n * 16 + fr;
            bf16x8 k0 = *(const bf16x8*)(Kd + row * 128 + ((kg ^ (row & 7)) << 4));
            bf16x8 k1 = *(const bf16x8*)(Kd + row * 128 + (((4 + kg) ^ (row & 7)) << 4));
            f32x4 sa = {0.0f, 0.0f, 0.0f, 0.0f};
            sa = __builtin_amdgcn_mfma_f32_16x16x32_bf16(k0, qf0, sa, 0, 0, 0);
            sa = __builtin_amdgcn_mfma_f32_16x16x32_bf16(k1, qf1, sa, 0, 0, 0);
            sfr[n] = sa;
        }
        const int qoff = w * 16 + fr;
#pragma unroll
        for (int n = 0; n < 4; ++n)
#pragma unroll
            for (int j = 0; j < 4; ++j) {
                float v = sfr[n][j] * 0.125f;
                if (st == diag && (n * 16 + kg * 4 + j) > qoff) v = -1e30f;
                sfr[n][j] = v;
            }
        // online softmax (state per lane, q = fr)
        float tm = -1e30f;
#pragma unroll
        for (int n = 0; n < 4; ++n)
#pragma unroll
            for (int j = 0; j < 4; ++j) tm = fmaxf(tm, sfr[n][j]);
        tm = fmaxf(tm, __shfl_xor(tm, 16));
        tm = fmaxf(tm, __shfl_xor(tm, 32));
        const float mnew = fmaxf(m_r, tm);
        const float fac = __expf(m_r - mnew);
        m_r = mnew;
        l_r *= fac;
        const float ff0 = __shfl(fac, kg * 4 + 0);
        const float ff1 = __shfl(fac, kg * 4 + 1);
        const float ff2 = __shfl(fac, kg * 4 + 2);
        const float ff3 = __shfl(fac, kg * 4 + 3);
#pragma unroll
        for (int nf = 0; nf < 4; ++nf) {
            o[nf][0] *= ff0; o[nf][1] *= ff1; o[nf][2] *= ff2; o[nf][3] *= ff3;
        }
        // exp, pack to bf16, write P rows to per-wave LDS
#pragma unroll
        for (int n = 0; n < 4; ++n) {
            float e0 = __expf(sfr[n][0] - mnew);
            float e1 = __expf(sfr[n][1] - mnew);
            float e2 = __expf(sfr[n][2] - mnew);
            float e3 = __expf(sfr[n][3] - mnew);
            l_r += (e0 + e1) + (e2 + e3);
            uint2 pv;
            pv.x = pack2(e0, e1);
            pv.y = pack2(e2, e3);
            *(uint2*)(Pw + n * 32 + kg * 8) = pv;
        }
        // PV: A = P[q=fr][s], B = V^T[d][s]
#pragma unroll
        for (int ks = 0; ks < 2; ++ks) {
            uint2 a0 = *(const uint2*)(Pw + ks * 64 + kg * 16);
            uint2 a1 = *(const uint2*)(Pw + ks * 64 + kg * 16 + 8);
            union { uint4 u; bf16x8 v; } pa;
            pa.u = make_uint4(a0.x, a0.y, a1.x, a1.y);
#pragma unroll
            for (int nf = 0; nf < 4; ++nf) {
                const int row = nf * 16 + fr;
                bf16x8 vf = *(const bf16x8*)(Vd + row * 128 + (((ks * 4 + kg) ^ (row & 7)) << 4));
                o[nf] = __builtin_amdgcn_mfma_f32_16x16x32_bf16(pa.v, vf, o[nf], 0, 0, 0);
            }
        }
        __syncthreads();
    }

    l_r += __shfl_xor(l_r, 16);
    l_r += __shfl_xor(l_r, 32);
    const float inv = 1.0f / l_r;
    const float iv0 = __shfl(inv, kg * 4 + 0);
    const float iv1 = __shfl(inv, kg * 4 + 1);
    const float iv2 = __shfl(inv, kg * 4 + 2);
    const float iv3 = __shfl(inv, kg * 4 + 3);
#pragma unroll
    for (int nf = 0; nf < 4; ++nf) {
        const size_t base = (size_t)(b * 1024 + q0) * 768 + h * 64 + nf * 16 + fr;
        attnb[base + (size_t)(kg * 4 + 0) * 768] = f2bf(o[nf][0] * iv0);
        attnb[base + (size_t)(kg * 4 + 1) * 768] = f2bf(o[nf][1] * iv1);
        attnb[base + (size_t)(kg * 4 + 2) * 768] = f2bf(o[nf][2] * iv2);
        attnb[base + (size_t)(kg * 4 + 3) * 768] = f2bf(o[nf][3] * iv3);
    }
}

// ---------------- host ----------------
extern "C" void kernel_launch(void* const* d_in, const int* in_sizes, int n_in,
                              void* d_out, int out_size, void* d_ws, size_t ws_size,
                              hipStream_t stream) {
    (void)in_sizes; (void)n_in; (void)out_size; (void)ws_size;
    const int*   idxp   = (const int*)d_in[0];
    const float* wte    = (const float*)d_in[1];
    const float* wpe    = (const float*)d_in[2];
    const float* ln1_w  = (const float*)d_in[3];
    const float* ln1_b  = (const float*)d_in[4];
    const float* wq_w   = (const float*)d_in[5];
    const float* wq_b   = (const float*)d_in[6];
    const float* kva_w  = (const float*)d_in[7];
    const float* kva_b  = (const float*)d_in[8];
    const float* kvb_w  = (const float*)d_in[9];
    const float* kvb_b  = (const float*)d_in[10];
    const float* out_w  = (const float*)d_in[11];
    const float* out_b  = (const float*)d_in[12];
    const float* ln2_w  = (const float*)d_in[13];
    const float* ln2_b  = (const float*)d_in[14];
    const float* fc_w   = (const float*)d_in[15];
    const float* fc_b   = (const float*)d_in[16];
    const float* proj_w = (const float*)d_in[17];
    const float* proj_b = (const float*)d_in[18];
    const float* lnf_w  = (const float*)d_in[19];
    const float* lnf_b  = (const float*)d_in[20];

    char* ws = (char*)d_ws;
    size_t off = 0;
    auto alloc = [&](size_t bytes) -> char* {
        char* p = ws + off;
        off += (bytes + 255) & ~(size_t)255;
        return p;
    };
    ushortT* wqkvaT = (ushortT*)alloc((size_t)12 * 1024 * 768 * 2);
    ushortT* kvbT   = (ushortT*)alloc((size_t)12 * 1536 * 256 * 2);
    ushortT* outT   = (ushortT*)alloc((size_t)12 * 768 * 768 * 2);
    ushortT* fcT    = (ushortT*)alloc((size_t)12 * 3072 * 768 * 2);
    ushortT* projT  = (ushortT*)alloc((size_t)12 * 768 * 3072 * 2);
    ushortT* wteB   = (ushortT*)alloc((size_t)50304 * 768 * 2);
    float* cosT = (float*)alloc((size_t)1024 * 32 * 4);
    float* sinT = (float*)alloc((size_t)1024 * 32 * 4);
    float*   x     = (float*)alloc((size_t)2048 * 768 * 4);
    ushortT* h     = (ushortT*)alloc((size_t)2048 * 768 * 2);
    ushortT* qbuf  = (ushortT*)alloc((size_t)2048 * 768 * 2);
    ushortT* lat   = (ushortT*)alloc((size_t)2048 * 256 * 2);
    ushortT* kvbuf = (ushortT*)alloc((size_t)2048 * 768 * 2);   // K only
    ushortT* vTb   = (ushortT*)alloc((size_t)24 * 64 * 1024 * 2);  // [b][h][d][t]
    ushortT* attnb = (ushortT*)alloc((size_t)2048 * 768 * 2);
    ushortT* fca   = (ushortT*)alloc((size_t)2048 * 3072 * 2);

    const dim3 blkT(32, 8);
    transpose_cvt_kernel<<<dim3(24, 24, 12), blkT, 0, stream>>>(wq_w,  wqkvaT, 768, 768,  0,   (size_t)1024 * 768);
    transpose_cvt_kernel<<<dim3(8,  24, 12), blkT, 0, stream>>>(kva_w, wqkvaT, 768, 256,  768, (size_t)1024 * 768);
    transpose_cvt_kernel<<<dim3(48, 8,  12), blkT, 0, stream>>>(kvb_w, kvbT,   256, 1536, 0,   (size_t)1536 * 256);
    transpose_cvt_kernel<<<dim3(24, 24, 12), blkT, 0, stream>>>(out_w, outT,   768, 768,  0,   (size_t)768 * 768);
    transpose_cvt_kernel<<<dim3(96, 24, 12), blkT, 0, stream>>>(fc_w,  fcT,    768, 3072, 0,   (size_t)3072 * 768);
    transpose_cvt_kernel<<<dim3(24, 96, 12), blkT, 0, stream>>>(proj_w, projT, 3072, 768, 0,   (size_t)768 * 3072);
    cvt_wte_kernel<<<37728, 256, 0, stream>>>(wte, wteB);
    rope_tables_kernel<<<128, 256, 0, stream>>>(cosT, sinT);
    embed_kernel<<<6144, 256, 0, stream>>>(idxp, wte, wpe, x);

    for (int l = 0; l < 12; ++l) {
        ln_kernel<<<2048, 256, 0, stream>>>(x, ln1_w + l * 768, ln1_b + l * 768, h);
        // fused q | kv_latent
        gemm128<8><<<dim3(16, 8), 256, 0, stream>>>(
            h, 768, wqkvaT + (size_t)l * 1024 * 768, 768,
            768, 768, 1024, wq_b + l * 768, kva_b + l * 256,
            qbuf, 768, lat, 256, 0, nullptr, nullptr, 0, 0);
        // kv = lat @ kvb: K part -> kvbuf rows, V part -> vT transposed
        gemm128<8><<<dim3(16, 12), 256, 0, stream>>>(
            lat, 256, kvbT + (size_t)l * 1536 * 256, 256,
            256, 768, 1536, kvb_b + l * 1536, kvb_b + l * 1536 + 768,
            kvbuf, 768, vTb, 0, 1, nullptr, nullptr, 0, 0);
        rope_apply2_kernel<<<6144, 256, 0, stream>>>(qbuf, kvbuf, cosT, sinT);
        attn_mfma<<<dim3(16, 24), 256, 0, stream>>>(qbuf, kvbuf, vTb, attnb);
        gemm128<4><<<dim3(16, 12), 256, 0, stream>>>(
            attnb, 768, outT + (size_t)l * 768 * 768, 768,
            768, 768, 768, out_b + l * 768, nullptr,
            nullptr, 0, nullptr, 0, 0, x, x, 768, 0);
        ln_kernel<<<2048, 256, 0, stream>>>(x, ln2_w + l * 768, ln2_b + l * 768, h);
        gemm128<8><<<dim3(16, 24), 256, 0, stream>>>(
            h, 768, fcT + (size_t)l * 3072 * 768, 768,
            768, 3072, 3072, fc_b + l * 3072, nullptr,
            fca, 3072, nullptr, 0, 0, nullptr, nullptr, 0, 1);
        gemm128<4><<<dim3(16, 12), 256, 0, stream>>>(
            fca, 3072, projT + (size_t)l * 768 * 3072, 3072,
            3072, 768, 768, proj_b + l * 768, nullptr,
            nullptr, 0, nullptr, 0, 0, x, x, 768, 0);
    }
    ln_kernel<<<2048, 256, 0, stream>>>(x, lnf_w, lnf_b, h);
    gemm128<8><<<dim3(16, 393), 256, 0, stream>>>(
        h, 768, wteB, 768,
        768, 50304, 50257, nullptr, nullptr,
        nullptr, 0, nullptr, 0, 0, nullptr, (float*)d_out, 50257, 0);
}